// Round 9
// baseline (293.584 us; speedup 1.0000x reference)
//
#include <hip/hip_runtime.h>
#include <stdint.h>

#define EPSQ 1e-8f

typedef __attribute__((ext_vector_type(4))) int i32x4;
typedef __attribute__((ext_vector_type(8))) unsigned short u16x8;

// ---- monotone float<->uint encoding so atomicMax(unsigned) orders floats ----
__device__ __forceinline__ unsigned enc_f(float f) {
    unsigned u = __float_as_uint(f);
    return (u & 0x80000000u) ? ~u : (u | 0x80000000u);
}
__device__ __forceinline__ float dec_f(unsigned u) {
    return (u & 0x80000000u) ? __uint_as_float(u & 0x7fffffffu)
                             : __uint_as_float(~u);
}

__device__ __forceinline__ float wave_max_f(float v) {
    #pragma unroll
    for (int off = 32; off; off >>= 1) v = fmaxf(v, __shfl_xor(v, off));
    return v;
}
__device__ __forceinline__ int wave_sum_i(int v) {
    #pragma unroll
    for (int off = 32; off; off >>= 1) v += __shfl_xor(v, off);
    return v;
}

// ---- wave-per-row weight quant: row in registers, one global read, no LDS --
template<int CNT>
__device__ __forceinline__ void quant_row_wave(
    const float4* __restrict__ wr, char4* __restrict__ qr, int lane,
    float* __restrict__ s_out, int* __restrict__ rs_out, int row) {
    float4 v[CNT];
    float m = 0.0f;
    #pragma unroll
    for (int c = 0; c < CNT; c++) {
        v[c] = wr[lane + 64 * c];
        m = fmaxf(m, fmaxf(fmaxf(fabsf(v[c].x), fabsf(v[c].y)),
                           fmaxf(fabsf(v[c].z), fabsf(v[c].w))));
    }
    m = wave_max_f(m);
    float s = fmaxf(m, EPSQ) / 127.0f;   // same fp32 ops as reference
    int isum = 0;
    #pragma unroll
    for (int c = 0; c < CNT; c++) {
        int a = min(max((int)rintf(v[c].x / s), -128), 127);
        int b = min(max((int)rintf(v[c].y / s), -128), 127);
        int c2 = min(max((int)rintf(v[c].z / s), -128), 127);
        int d = min(max((int)rintf(v[c].w / s), -128), 127);
        isum += a + b + c2 + d;
        char4 cc; cc.x = (char)a; cc.y = (char)b; cc.z = (char)c2; cc.w = (char)d;
        qr[lane + 64 * c] = cc;
    }
    isum = wave_sum_i(isum);
    if (lane == 0) { s_out[row] = s; rs_out[row] = isum; }
}

// ---------------- fused prep: x global max (atomic) + w1/w2 row quant ------
// blocks [0,2048): x-max grid-stride -> atomicMax(slots[0]) (slots pre-zeroed
// by hipMemsetAsync; enc_f(f) > 0 for all reals so 0 is the identity);
// [2048,3072): w1, 4 rows/block (1 wave/row, no barriers);
// [3072,3328): w2, 4 rows/block.
__global__ __launch_bounds__(256) void k_prep(
    const float4* __restrict__ x, long n4x, unsigned* __restrict__ slots,
    const float* __restrict__ w1, signed char* __restrict__ w1q,
    float* __restrict__ sw1, int* __restrict__ rs1,
    const float* __restrict__ w2, signed char* __restrict__ w2q,
    float* __restrict__ sw2, int* __restrict__ rs2) {
    __shared__ float sm[4];
    int b = blockIdx.x;
    int t = threadIdx.x;
    int lane = t & 63;
    int w = t >> 6;
    if (b < 2048) {
        long i = (long)b * 256 + t;
        float m = -3.4e38f;
        for (; i < n4x; i += 2048L * 256) {
            float4 v = x[i];
            m = fmaxf(fmaxf(m, fmaxf(v.x, v.y)), fmaxf(v.z, v.w));
        }
        m = wave_max_f(m);
        if (lane == 0) sm[w] = m;
        __syncthreads();
        if (t == 0) {
            m = fmaxf(fmaxf(sm[0], sm[1]), fmaxf(sm[2], sm[3]));
            atomicMax(slots + 0, enc_f(m));   // device-scope (m20)
        }
        return;
    }
    if (b < 3072) {
        int row = (b - 2048) * 4 + w;        // w1: [4096][1024]
        quant_row_wave<4>((const float4*)(w1 + (long)row * 1024),
                          (char4*)(w1q + (long)row * 1024), lane, sw1, rs1, row);
    } else {
        int row = (b - 3072) * 4 + w;        // w2: [1024][4096]
        quant_row_wave<16>((const float4*)(w2 + (long)row * 4096),
                           (char4*)(w2q + (long)row * 4096), lane, sw2, rs2, row);
    }
}

// ---------------- activation quant x -> int8 (offset -128) ------------------
// Reads the finished global max from slots[0] (prep completed, stream order).
__global__ __launch_bounds__(256) void k_quant_act(
    const float4* __restrict__ in, char4* __restrict__ out, long n4,
    const unsigned* __restrict__ slots) {
    float m = dec_f(slots[0]);
    float s = fmaxf(m, EPSQ) / 255.0f;
    long i = (long)blockIdx.x * 256 + threadIdx.x;
    for (; i < n4; i += (long)gridDim.x * 256) {
        float4 v = in[i];
        int a = min(max((int)rintf(v.x / s), 0), 255) - 128;
        int b = min(max((int)rintf(v.y / s), 0), 255) - 128;
        int c = min(max((int)rintf(v.z / s), 0), 255) - 128;
        int d = min(max((int)rintf(v.w / s), 0), 255) - 128;
        char4 cc; cc.x = (char)a; cc.y = (char)b; cc.z = (char)c; cc.w = (char)d;
        out[i] = cc;
    }
}

// -------- requant: u16 (per-block scale) -> uint8 global units, offset -128 --
// GEMM1 tiles are 128x128: block idx = (m>>7)*32 + (f>>7). Vectorized:
// ushort8 (16B) loads, int2 (8B) packed stores; e..e+7 stay in one f-block.
__global__ __launch_bounds__(256) void k_requant(
    const u16x8* __restrict__ h16, int2* __restrict__ hq,
    const float* __restrict__ sblk, const unsigned* __restrict__ slots, long n8) {
    float s_h = fmaxf(dec_f(slots[1]), EPSQ) / 255.0f;
    float inv = 1.0f / (65535.0f * s_h);
    long i = (long)blockIdx.x * 256 + threadIdx.x;
    for (; i < n8; i += (long)gridDim.x * 256) {
        long e = i << 3;
        int m = (int)(e >> 12);
        int f = (int)(e & 4095);
        float fq = sblk[(m >> 7) * 32 + (f >> 7)] * inv;
        u16x8 u = h16[i];
        unsigned lo = 0, hi = 0;
        #pragma unroll
        for (int k = 0; k < 4; k++) {
            int q = min(max((int)rintf((float)u[k] * fq), 0), 255) - 128;
            lo |= ((unsigned)q & 255u) << (8 * k);
        }
        #pragma unroll
        for (int k = 0; k < 4; k++) {
            int q = min(max((int)rintf((float)u[k + 4] * fq), 0), 255) - 128;
            hi |= ((unsigned)q & 255u) << (8 * k);
        }
        hq[i] = make_int2((int)lo, (int)hi);
    }
}

// ---------------- async global -> LDS, 16B per lane ----------------
__device__ __forceinline__ void gl_lds16(const signed char* g, signed char* l) {
    __builtin_amdgcn_global_load_lds(
        (const __attribute__((address_space(1))) unsigned int*)g,
        (__attribute__((address_space(3))) unsigned int*)l, 16, 0, 0);
}

// ---------------- i8 GEMM, 16x16x64 MFMA, 128 x 128 tile, BK=128 ------------
// R4/R8-VERIFIED config (79-81 us/GEMM): single-buffered 2-barrier K-step,
// 16-row-panel LDS layout, 64B-per-row staging, wave-contiguous ds_read_b128,
// LDS-transposed coalesced epilogues, bijective XCD swizzle. GEMM-schedule
// levers closed by experiment: dbuf (3/3 container kills), BK=256 (+8us),
// B-direct (+29us), 4-block co-residency (null). Do not re-attempt.
// MODE 0: fp32 store (GEMM2). MODE 3: GEMM1 relu -> block max -> u16 store.
template<int MODE, int BM, int NW>
__global__ __launch_bounds__(NW * 64, (MODE == 0 ? 3 : 4)) void k_gemm_i8(
    const signed char* __restrict__ A,   // [M][K]
    const signed char* __restrict__ B,   // [N][K]
    const float* __restrict__ s_w,       // [N]
    const int* __restrict__ rowsum,      // [N]
    const float* __restrict__ bias,      // [N]
    const unsigned* __restrict__ act_slot,
    float* __restrict__ Cf,              // MODE 0
    unsigned short* __restrict__ H16,    // MODE 3
    float* __restrict__ sblk,            // MODE 3
    unsigned* __restrict__ omax_slot,    // MODE 3 target
    int M, int N, long K) {
    constexpr int ASZ = BM * 128;        // 16 KB (BM=128)
    constexpr int BSZ = 128 * 128;       // 16 KB
    __shared__ __align__(16) signed char SH[ASZ + BSZ];
    __shared__ float red[NW];

    const int t    = threadIdx.x;
    const int lane = t & 63;
    const int w    = t >> 6;
    // bijective XCD-chunked swizzle (nwg % 8 == 0: 2048 / 512)
    const unsigned nwg = gridDim.x * gridDim.y;
    const unsigned wg  = blockIdx.y * gridDim.x + blockIdx.x;
    const unsigned swg = (wg & 7u) * (nwg >> 3) + (wg >> 3);
    const int bx = (int)(swg % gridDim.x);
    const int by = (int)(swg / gridDim.x);
    const int m0 = by * BM;
    const int n0 = bx * 128;
    const int mr   = lane & 15;   // row-in-panel / C-D col-in-16
    const int qq   = lane >> 4;   // k-group / C-D row-quad
    constexpr int PB = 8 / NW;    // B panels per wave (=2 at NW=4)

    const signed char* a0 = A + (long)(m0 + w * 32 + mr) * K + qq * 16;
    const signed char* b0 = B + (long)(n0 + w * PB * 16 + mr) * K + qq * 16;
    signed char* ad = SH + w * 4096 + lane * 16;
    signed char* bd = SH + ASZ + w * PB * 2048 + lane * 16;

    const int wrow = (w >> 1) * 64;
    const int wcol = (w & 1) * 64;
    const int a_base = (w >> 1) * 8192 + lane * 16;
    const int b_base = (w & 1) * 8192 + lane * 16;

    i32x4 acc[4][4];
    #pragma unroll
    for (int i = 0; i < 4; i++)
        #pragma unroll
        for (int j = 0; j < 4; j++) acc[i][j] = (i32x4){0, 0, 0, 0};

    for (long k0 = 0; k0 < K; k0 += 128) {
        __syncthreads();                    // previous iter's reads done
        gl_lds16(a0 + k0,               ad);
        gl_lds16(a0 + k0 + 64,          ad + 1024);
        gl_lds16(a0 + k0 + 16 * K,      ad + 2048);
        gl_lds16(a0 + k0 + 16 * K + 64, ad + 3072);
        #pragma unroll
        for (int p = 0; p < PB; p++) {
            gl_lds16(b0 + k0 + (long)p * 16 * K,      bd + p * 2048);
            gl_lds16(b0 + k0 + (long)p * 16 * K + 64, bd + p * 2048 + 1024);
        }
        __syncthreads();                    // vmcnt(0) drain: staging visible

        #pragma unroll
        for (int kk = 0; kk < 2; kk++) {
            i32x4 af[4], bf[4];
            #pragma unroll
            for (int i = 0; i < 4; i++)
                af[i] = *(const i32x4*)(SH + a_base + i * 2048 + kk * 1024);
            #pragma unroll
            for (int j = 0; j < 4; j++)
                bf[j] = *(const i32x4*)(SH + ASZ + b_base + j * 2048 + kk * 1024);
            #pragma unroll
            for (int i = 0; i < 4; i++)
                #pragma unroll
                for (int j = 0; j < 4; j++)
                    acc[i][j] = __builtin_amdgcn_mfma_i32_16x16x64_i8(
                        af[i], bf[j], acc[i][j], 0, 0, 0);
        }
    }

    // ---- epilogue ----
    const float s_act = fmaxf(dec_f(*act_slot), EPSQ) / 255.0f;

    float sscv[4], bintv[4]; int icorv[4];
    #pragma unroll
    for (int j = 0; j < 4; j++) {
        int gn = n0 + wcol + j * 16 + mr;
        sscv[j]  = s_act * s_w[gn];
        bintv[j] = rintf(bias[gn] / sscv[j]);
        icorv[j] = 128 * rowsum[gn];
    }

    if (MODE == 3) {
        float lmax = 0.0f;
        #pragma unroll
        for (int j = 0; j < 4; j++) {
            int im = -2147483647 - 1;   // h monotone in integer acc per column
            #pragma unroll
            for (int i = 0; i < 4; i++)
                #pragma unroll
                for (int r = 0; r < 4; r++) im = max(im, acc[i][j][r]);
            lmax = fmaxf(lmax, sscv[j] * ((float)(im + icorv[j]) + bintv[j]));
        }
        lmax = wave_max_f(fmaxf(lmax, 0.0f));
        if (lane == 0) red[w] = lmax;
        __syncthreads();                 // red ready + K-loop LDS reads done
        float bm = red[0];
        #pragma unroll
        for (int i = 1; i < NW; i++) bm = fmaxf(bm, red[i]);
        if (t == 0) {
            sblk[by * gridDim.x + bx] = bm;
            atomicMax(omax_slot, enc_f(bm));
        }
        float inv = 65535.0f / fmaxf(bm, EPSQ);

        // single-phase [128][128] u16 tile in SH (32 KB), qq-keyed 16-col
        // XOR swizzle (write conflict-free), then 16B/lane coalesced stores.
        unsigned short* tile = (unsigned short*)SH;
        #pragma unroll
        for (int j = 0; j < 4; j++) {
            int cg = ((wcol + j * 16) >> 4) ^ qq;     // permuted 16-col group
            #pragma unroll
            for (int i = 0; i < 4; i++) {
                #pragma unroll
                for (int r = 0; r < 4; r++) {
                    int lr = wrow + i * 16 + qq * 4 + r;
                    float h = fmaxf(
                        sscv[j] * ((float)(acc[i][j][r] + icorv[j]) + bintv[j]),
                        0.0f);
                    int u = min((int)rintf(h * inv), 65535);
                    tile[lr * 128 + cg * 16 + mr] = (unsigned short)u;
                }
            }
        }
        __syncthreads();                 // tile ready
        int tr = t >> 4, tc = t & 15;    // 256 thr: tr in [0,16)
        int cp = tc ^ (((tr >> 2) & 3) << 1);   // undo swizzle (qq from row)
        #pragma unroll
        for (int it = 0; it < 8; ++it) {
            int lr = it * 16 + tr;
            i32x4 v = *(const i32x4*)(tile + (long)lr * 128 + cp * 8);
            *(i32x4*)(H16 + (long)(m0 + lr) * N + n0 + tc * 8) = v;
        }
        return;
    }

    // MODE 0: fp32 output via two 64-row phases through 32 KB of SH
    float* tf = (float*)SH;              // [64][128] f32
    #pragma unroll
    for (int ph = 0; ph < 2; ++ph) {
        __syncthreads();                 // K-loop / prev-phase reads done
        if ((w >> 1) == ph) {            // waves owning rows [64ph,64ph+64)
            #pragma unroll
            for (int j = 0; j < 4; j++) {
                int cg = ((wcol + j * 16) >> 4) ^ qq;
                #pragma unroll
                for (int i = 0; i < 4; i++) {
                    #pragma unroll
                    for (int r = 0; r < 4; r++) {
                        int lrl = i * 16 + qq * 4 + r;
                        tf[lrl * 128 + cg * 16 + mr] =
                            sscv[j] * ((float)(acc[i][j][r] + icorv[j]) + bintv[j]);
                    }
                }
            }
        }
        __syncthreads();                 // tile half ready
        int tr = t >> 5, tc = t & 31;    // 256 thr: tr in [0,8)
        #pragma unroll
        for (int it = 0; it < 8; ++it) {
            int lrl = it * 8 + tr;
            int sz = (lrl >> 2) & 3;     // writer's qq
            i32x4 v = *(const i32x4*)(tf + lrl * 128 + (tc ^ (sz << 2)) * 4);
            *(i32x4*)(Cf + (long)(m0 + ph * 64 + lrl) * N + n0 + tc * 4) = v;
        }
    }
}

extern "C" void kernel_launch(void* const* d_in, const int* in_sizes, int n_in,
                              void* d_out, int out_size, void* d_ws, size_t ws_size,
                              hipStream_t stream) {
    const float* x  = (const float*)d_in[0];  // [4,2048,1024]
    const float* w1 = (const float*)d_in[1];  // [4096,1024]
    const float* b1 = (const float*)d_in[2];  // [4096]
    const float* w2 = (const float*)d_in[3];  // [1024,4096]
    const float* b2 = (const float*)d_in[4];  // [1024]
    float* out = (float*)d_out;               // [4,2048,1024] fp32

    const int M = 8192, D = 1024, F = 4096;

    char* ws = (char*)d_ws;
    size_t off = 0;
    unsigned* slots = (unsigned*)ws;               off += 256;  // [0]=max x, [1]=max h
    signed char* xi  = (signed char*)(ws + off);   off += (size_t)M * D;      // 8 MB
    signed char* w1q = (signed char*)(ws + off);   off += (size_t)F * D;      // 4 MB
    signed char* w2q = (signed char*)(ws + off);   off += (size_t)D * F;      // 4 MB
    float* sw1 = (float*)(ws + off);               off += (size_t)F * 4;
    float* sw2 = (float*)(ws + off);               off += (size_t)D * 4;
    int* rs1   = (int*)(ws + off);                 off += (size_t)F * 4;
    int* rs2   = (int*)(ws + off);                 off += (size_t)D * 4;
    signed char* hq = (signed char*)(ws + off);    off += (size_t)M * F;      // 32 MB
    unsigned short* h16 = (unsigned short*)(ws + off); off += (size_t)M * F * 2; // 64 MB
    float* sblk = (float*)(ws + off);              off += 2048 * 4;           // 64x32 tiles

    // zero the two atomic slots (enc_f(f) > 0 for all reals; 0 = identity)
    hipMemsetAsync(slots, 0, 256, stream);

    // x-max: 2048 blocks; w1: 1024 blocks (4 rows each); w2: 256 blocks
    k_prep<<<dim3(2048 + 1024 + 256), dim3(256), 0, stream>>>(
        (const float4*)x, (long)M * D / 4, slots,
        w1, w1q, sw1, rs1, w2, w2q, sw2, rs2);
    k_quant_act<<<dim3(2048), dim3(256), 0, stream>>>(
        (const float4*)x, (char4*)xi, (long)M * D / 4, slots);
    // GEMM1 single pass: relu -> block-scaled u16 + block/global max
    k_gemm_i8<3, 128, 4><<<dim3(F / 128, M / 128), dim3(256), 0, stream>>>(
        xi, w1q, sw1, rs1, b1, slots + 0, nullptr, h16, sblk, slots + 1,
        M, F, (long)D);
    // u16 -> final uint8 units (offset -128)
    k_requant<<<dim3(2048), dim3(256), 0, stream>>>(
        (const u16x8*)h16, (int2*)hq, sblk, slots, (long)M * F / 8);
    // GEMM2: fp32 output
    k_gemm_i8<0, 128, 4><<<dim3(D / 128, M / 128), dim3(256), 0, stream>>>(
        hq, w2q, sw2, rs2, b2, slots + 1, out, nullptr, nullptr, nullptr,
        M, D, (long)F);

    (void)in_sizes; (void)n_in; (void)out_size; (void)ws_size;
}

// Round 10
// 272.341 us; speedup vs baseline: 1.0780x; 1.0780x over previous
//
#include <hip/hip_runtime.h>
#include <stdint.h>

#define EPSQ 1e-8f

typedef __attribute__((ext_vector_type(4))) int i32x4;

// ---- monotone float<->uint encoding so atomicMax(unsigned) orders floats ----
__device__ __forceinline__ unsigned enc_f(float f) {
    unsigned u = __float_as_uint(f);
    return (u & 0x80000000u) ? ~u : (u | 0x80000000u);
}
__device__ __forceinline__ float dec_f(unsigned u) {
    return (u & 0x80000000u) ? __uint_as_float(u & 0x7fffffffu)
                             : __uint_as_float(~u);
}

__device__ __forceinline__ float wave_max_f(float v) {
    #pragma unroll
    for (int off = 32; off; off >>= 1) v = fmaxf(v, __shfl_xor(v, off));
    return v;
}
__device__ __forceinline__ int wave_sum_i(int v) {
    #pragma unroll
    for (int off = 32; off; off >>= 1) v += __shfl_xor(v, off);
    return v;
}

// ---------------- fused prep: x partial max + per-row quant of w1, w2 -------
__global__ __launch_bounds__(256) void k_prep(
    const float4* __restrict__ x, long n4x, float* __restrict__ partials,
    const float* __restrict__ w1, signed char* __restrict__ w1q,
    float* __restrict__ sw1, int* __restrict__ rs1,
    const float* __restrict__ w2, signed char* __restrict__ w2q,
    float* __restrict__ sw2, int* __restrict__ rs2) {
    __shared__ float sm[4];
    __shared__ int   si[4];
    int b = blockIdx.x;
    int wid = threadIdx.x >> 6;
    if (b < 2048) {
        long i = (long)b * 256 + threadIdx.x;
        float m = -3.4e38f;
        for (; i < n4x; i += 2048L * 256) {
            float4 v = x[i];
            m = fmaxf(fmaxf(m, fmaxf(v.x, v.y)), fmaxf(v.z, v.w));
        }
        m = wave_max_f(m);
        if ((threadIdx.x & 63) == 0) sm[wid] = m;
        __syncthreads();
        if (threadIdx.x == 0)
            partials[b] = fmaxf(fmaxf(sm[0], sm[1]), fmaxf(sm[2], sm[3]));
        return;
    }
    const float* w; signed char* q; float* s_out; int* rs_out; int row, L;
    if (b < 2048 + 4096) { row = b - 2048; w = w1; q = w1q; s_out = sw1; rs_out = rs1; L = 1024; }
    else                 { row = b - 6144; w = w2; q = w2q; s_out = sw2; rs_out = rs2; L = 4096; }

    const float4* wr = (const float4*)(w + (long)row * L);
    int n4 = L >> 2;
    float m = 0.0f;
    for (int i = threadIdx.x; i < n4; i += 256) {
        float4 v = wr[i];
        m = fmaxf(m, fmaxf(fmaxf(fabsf(v.x), fabsf(v.y)),
                           fmaxf(fabsf(v.z), fabsf(v.w))));
    }
    m = wave_max_f(m);
    if ((threadIdx.x & 63) == 0) sm[wid] = m;
    __syncthreads();
    m = fmaxf(fmaxf(sm[0], sm[1]), fmaxf(sm[2], sm[3]));
    float s = fmaxf(m, EPSQ) / 127.0f;   // same fp32 ops as reference

    char4* qr = (char4*)(q + (long)row * L);
    int isum = 0;
    for (int i = threadIdx.x; i < n4; i += 256) {
        float4 v = wr[i];
        int a = min(max((int)rintf(v.x / s), -128), 127);
        int bb = min(max((int)rintf(v.y / s), -128), 127);
        int c = min(max((int)rintf(v.z / s), -128), 127);
        int d = min(max((int)rintf(v.w / s), -128), 127);
        isum += a + bb + c + d;
        char4 cc; cc.x = (char)a; cc.y = (char)bb; cc.z = (char)c; cc.w = (char)d;
        qr[i] = cc;
    }
    isum = wave_sum_i(isum);
    if ((threadIdx.x & 63) == 0) si[wid] = isum;
    __syncthreads();
    if (threadIdx.x == 0) {
        s_out[row]  = s;
        rs_out[row] = si[0] + si[1] + si[2] + si[3];
    }
}

// ---------------- activation quant x -> int8 (offset -128) ------------------
__global__ __launch_bounds__(256) void k_quant_act(
    const float4* __restrict__ in, char4* __restrict__ out, long n4,
    const float* __restrict__ partials, unsigned* __restrict__ slots) {
    __shared__ float sm[4];
    float m = -3.4e38f;
    for (int i = threadIdx.x; i < 2048; i += 256) m = fmaxf(m, partials[i]);
    m = wave_max_f(m);
    if ((threadIdx.x & 63) == 0) sm[threadIdx.x >> 6] = m;
    __syncthreads();
    m = fmaxf(fmaxf(sm[0], sm[1]), fmaxf(sm[2], sm[3]));
    if (blockIdx.x == 0 && threadIdx.x == 0) {
        slots[0] = enc_f(m);
        slots[1] = 0u;     // 0 < any encoded real value
    }
    float s = fmaxf(m, EPSQ) / 255.0f;
    long i = (long)blockIdx.x * 256 + threadIdx.x;
    for (; i < n4; i += (long)gridDim.x * 256) {
        float4 v = in[i];
        int a = min(max((int)rintf(v.x / s), 0), 255) - 128;
        int b = min(max((int)rintf(v.y / s), 0), 255) - 128;
        int c = min(max((int)rintf(v.z / s), 0), 255) - 128;
        int d = min(max((int)rintf(v.w / s), 0), 255) - 128;
        char4 cc; cc.x = (char)a; cc.y = (char)b; cc.z = (char)c; cc.w = (char)d;
        out[i] = cc;
    }
}

// -------- requant: u16 (per-block scale) -> uint8 global units, offset -128 --
// element e: m = e>>12, f = e&4095 (F=4096); GEMM1 block = (m>>8, f>>7),
// sblk idx = (m>>8)*32 + (f>>7)
__global__ __launch_bounds__(256) void k_requant(
    const ushort4* __restrict__ h16, char4* __restrict__ hq,
    const float* __restrict__ sblk, const unsigned* __restrict__ slots, long n4) {
    float s_h = fmaxf(dec_f(slots[1]), EPSQ) / 255.0f;
    float inv = 1.0f / (65535.0f * s_h);
    long i = (long)blockIdx.x * 256 + threadIdx.x;
    for (; i < n4; i += (long)gridDim.x * 256) {
        long e = i << 2;
        int m = (int)(e >> 12);
        int f = (int)(e & 4095);
        float fq = sblk[(m >> 8) * 32 + (f >> 7)] * inv;
        ushort4 u = h16[i];
        char4 cc;
        cc.x = (char)(min(max((int)rintf(u.x * fq), 0), 255) - 128);
        cc.y = (char)(min(max((int)rintf(u.y * fq), 0), 255) - 128);
        cc.z = (char)(min(max((int)rintf(u.z * fq), 0), 255) - 128);
        cc.w = (char)(min(max((int)rintf(u.w * fq), 0), 255) - 128);
        hq[i] = cc;
    }
}

// ---------------- async global -> LDS, 16B per lane ----------------
__device__ __forceinline__ void gl_lds16(const signed char* g, signed char* l) {
    __builtin_amdgcn_global_load_lds(
        (const __attribute__((address_space(1))) unsigned int*)g,
        (__attribute__((address_space(3))) unsigned int*)l, 16, 0, 0);
}

// ---------------- i8 GEMM, 16x16x64 MFMA, BM x 128 tile, BK=128 -------------
// PROVEN K-loop: single-buffered, 2-barrier K-step, 16-row-panel LDS layout,
// 64B-per-row staging chunks, wave-contiguous ds_read_b128. LDS-transposed
// coalesced epilogues + bijective XCD block swizzle. Best-measured config
// (R3: 273.2 us total). Levers closed by experiment: dbuf (3/3 container
// kills), BK=256 (+8us), B-direct (+29us), co-residency (null).
// MODE 0: fp32 store (GEMM2, BM=128/NW=4).
// MODE 3: single-pass GEMM1 (BM=256/NW=8): relu -> block max -> u16 store.
template<int MODE, int BM, int NW>
__global__ __launch_bounds__(NW * 64, (MODE == 0 ? 3 : 4)) void k_gemm_i8(
    const signed char* __restrict__ A,   // [M][K]
    const signed char* __restrict__ B,   // [N][K]
    const float* __restrict__ s_w,       // [N]
    const int* __restrict__ rowsum,      // [N]
    const float* __restrict__ bias,      // [N]
    const unsigned* __restrict__ act_slot,
    float* __restrict__ Cf,              // MODE 0
    unsigned short* __restrict__ H16,    // MODE 3
    float* __restrict__ sblk,            // MODE 3
    unsigned* __restrict__ omax_slot,    // MODE 3 target
    int M, int N, long K) {
    constexpr int ASZ = BM * 128;        // 32 KB (BM=256) / 16 KB (BM=128)
    constexpr int BSZ = 128 * 128;       // 16 KB
    __shared__ __align__(16) signed char SH[ASZ + BSZ];
    __shared__ float red[NW];

    const int t    = threadIdx.x;
    const int lane = t & 63;
    const int w    = t >> 6;
    // bijective XCD-chunked swizzle (nwg % 8 == 0: 1024 / 512)
    const unsigned nwg = gridDim.x * gridDim.y;
    const unsigned wg  = blockIdx.y * gridDim.x + blockIdx.x;
    const unsigned swg = (wg & 7u) * (nwg >> 3) + (wg >> 3);
    const int bx = (int)(swg % gridDim.x);
    const int by = (int)(swg / gridDim.x);
    const int m0 = by * BM;
    const int n0 = bx * 128;
    const int mr   = lane & 15;   // row-in-panel / C-D col-in-16
    const int qq   = lane >> 4;   // k-group / C-D row-quad
    constexpr int PB = 8 / NW;    // B panels per wave

    const signed char* a0 = A + (long)(m0 + w * 32 + mr) * K + qq * 16;
    const signed char* b0 = B + (long)(n0 + w * PB * 16 + mr) * K + qq * 16;
    signed char* ad = SH + w * 4096 + lane * 16;
    signed char* bd = SH + ASZ + w * PB * 2048 + lane * 16;

    const int wrow = (w >> 1) * 64;
    const int wcol = (w & 1) * 64;
    const int a_base = (w >> 1) * 8192 + lane * 16;
    const int b_base = (w & 1) * 8192 + lane * 16;

    i32x4 acc[4][4];
    #pragma unroll
    for (int i = 0; i < 4; i++)
        #pragma unroll
        for (int j = 0; j < 4; j++) acc[i][j] = (i32x4){0, 0, 0, 0};

    for (long k0 = 0; k0 < K; k0 += 128) {
        __syncthreads();                    // previous iter's reads done
        gl_lds16(a0 + k0,               ad);
        gl_lds16(a0 + k0 + 64,          ad + 1024);
        gl_lds16(a0 + k0 + 16 * K,      ad + 2048);
        gl_lds16(a0 + k0 + 16 * K + 64, ad + 3072);
        #pragma unroll
        for (int p = 0; p < PB; p++) {
            gl_lds16(b0 + k0 + (long)p * 16 * K,      bd + p * 2048);
            gl_lds16(b0 + k0 + (long)p * 16 * K + 64, bd + p * 2048 + 1024);
        }
        __syncthreads();                    // vmcnt(0) drain: staging visible

        #pragma unroll
        for (int kk = 0; kk < 2; kk++) {
            i32x4 af[4], bf[4];
            #pragma unroll
            for (int i = 0; i < 4; i++)
                af[i] = *(const i32x4*)(SH + a_base + i * 2048 + kk * 1024);
            #pragma unroll
            for (int j = 0; j < 4; j++)
                bf[j] = *(const i32x4*)(SH + ASZ + b_base + j * 2048 + kk * 1024);
            #pragma unroll
            for (int i = 0; i < 4; i++)
                #pragma unroll
                for (int j = 0; j < 4; j++)
                    acc[i][j] = __builtin_amdgcn_mfma_i32_16x16x64_i8(
                        af[i], bf[j], acc[i][j], 0, 0, 0);
        }
    }

    // ---- epilogue ----
    const float s_act = fmaxf(dec_f(*act_slot), EPSQ) / 255.0f;

    float sscv[4], bintv[4]; int icorv[4];
    #pragma unroll
    for (int j = 0; j < 4; j++) {
        int gn = n0 + wcol + j * 16 + mr;
        sscv[j]  = s_act * s_w[gn];
        bintv[j] = rintf(bias[gn] / sscv[j]);
        icorv[j] = 128 * rowsum[gn];
    }

    if (MODE == 3) {
        float lmax = 0.0f;
        #pragma unroll
        for (int j = 0; j < 4; j++) {
            int im = -2147483647 - 1;   // h monotone in integer acc per column
            #pragma unroll
            for (int i = 0; i < 4; i++)
                #pragma unroll
                for (int r = 0; r < 4; r++) im = max(im, acc[i][j][r]);
            lmax = fmaxf(lmax, sscv[j] * ((float)(im + icorv[j]) + bintv[j]));
        }
        lmax = wave_max_f(fmaxf(lmax, 0.0f));
        if (lane == 0) red[w] = lmax;
        __syncthreads();                 // red ready + all K-loop LDS reads done
        float bm = red[0];
        #pragma unroll
        for (int i = 1; i < NW; i++) bm = fmaxf(bm, red[i]);
        if (t == 0) {
            sblk[by * gridDim.x + bx] = bm;
            atomicMax(omax_slot, enc_f(bm));
        }
        float inv = 65535.0f / fmaxf(bm, EPSQ);

        // two half-tile phases through 32 KB of SH: [128][128] u16, with
        // qq-keyed 16-col XOR swizzle (write conflict-free), then 16B/lane
        // coalesced stores (full 256B row-runs).
        unsigned short* tile = (unsigned short*)SH;
        #pragma unroll
        for (int ph = 0; ph < 2; ++ph) {
            if ((w >> 2) == ph) {        // waves owning rows [128ph,128ph+128)
                int rbase = wrow & 127;
                #pragma unroll
                for (int j = 0; j < 4; j++) {
                    int cg = ((wcol + j * 16) >> 4) ^ qq;
                    #pragma unroll
                    for (int i = 0; i < 4; i++) {
                        #pragma unroll
                        for (int r = 0; r < 4; r++) {
                            int lrl = rbase + i * 16 + qq * 4 + r;
                            float h = fmaxf(
                                sscv[j] * ((float)(acc[i][j][r] + icorv[j]) + bintv[j]),
                                0.0f);
                            int u = min((int)rintf(h * inv), 65535);
                            tile[lrl * 128 + cg * 16 + mr] = (unsigned short)u;
                        }
                    }
                }
            }
            __syncthreads();             // tile half ready
            int tr = t >> 4, tc = t & 15;            // 512 thr: tr in [0,32)
            int cp = tc ^ (((tr >> 2) & 3) << 1);    // undo swizzle (qq from row)
            #pragma unroll
            for (int it = 0; it < 4; ++it) {
                int lrl = it * 32 + tr;
                i32x4 v = *(const i32x4*)(tile + lrl * 128 + cp * 8);
                *(i32x4*)(H16 + (long)(m0 + ph * 128 + lrl) * N + n0 + tc * 8) = v;
            }
            if (ph == 0) __syncthreads(); // half-tile reads done before reuse
        }
        return;
    }

    // MODE 0: fp32 output via two 64-row phases through 32 KB of SH
    float* tf = (float*)SH;              // [64][128] f32
    #pragma unroll
    for (int ph = 0; ph < 2; ++ph) {
        __syncthreads();                 // K-loop / prev-phase reads done
        if ((w >> 1) == ph) {            // waves owning rows [64ph,64ph+64)
            #pragma unroll
            for (int j = 0; j < 4; j++) {
                int cg = ((wcol + j * 16) >> 4) ^ qq;
                #pragma unroll
                for (int i = 0; i < 4; i++) {
                    #pragma unroll
                    for (int r = 0; r < 4; r++) {
                        int lrl = i * 16 + qq * 4 + r;
                        tf[lrl * 128 + cg * 16 + mr] =
                            sscv[j] * ((float)(acc[i][j][r] + icorv[j]) + bintv[j]);
                    }
                }
            }
        }
        __syncthreads();                 // tile half ready
        int tr = t >> 5, tc = t & 31;    // 256 thr: tr in [0,8)
        #pragma unroll
        for (int it = 0; it < 8; ++it) {
            int lrl = it * 8 + tr;
            int sz = (lrl >> 2) & 3;     // writer's qq
            i32x4 v = *(const i32x4*)(tf + lrl * 128 + (tc ^ (sz << 2)) * 4);
            *(i32x4*)(Cf + (long)(m0 + ph * 64 + lrl) * N + n0 + tc * 4) = v;
        }
    }
}

extern "C" void kernel_launch(void* const* d_in, const int* in_sizes, int n_in,
                              void* d_out, int out_size, void* d_ws, size_t ws_size,
                              hipStream_t stream) {
    const float* x  = (const float*)d_in[0];  // [4,2048,1024]
    const float* w1 = (const float*)d_in[1];  // [4096,1024]
    const float* b1 = (const float*)d_in[2];  // [4096]
    const float* w2 = (const float*)d_in[3];  // [1024,4096]
    const float* b2 = (const float*)d_in[4];  // [1024]
    float* out = (float*)d_out;               // [4,2048,1024] fp32

    const int M = 8192, D = 1024, F = 4096;

    char* ws = (char*)d_ws;
    size_t off = 0;
    unsigned* slots = (unsigned*)ws;               off += 256;  // [0]=max x, [1]=max h
    float* partials = (float*)(ws + off);          off += 2048 * 4;
    signed char* xi  = (signed char*)(ws + off);   off += (size_t)M * D;      // 8 MB
    signed char* w1q = (signed char*)(ws + off);   off += (size_t)F * D;      // 4 MB
    signed char* w2q = (signed char*)(ws + off);   off += (size_t)D * F;      // 4 MB
    float* sw1 = (float*)(ws + off);               off += (size_t)F * 4;
    float* sw2 = (float*)(ws + off);               off += (size_t)D * 4;
    int* rs1   = (int*)(ws + off);                 off += (size_t)F * 4;
    int* rs2   = (int*)(ws + off);                 off += (size_t)D * 4;
    signed char* hq = (signed char*)(ws + off);    off += (size_t)M * F;      // 32 MB
    unsigned short* h16 = (unsigned short*)(ws + off); off += (size_t)M * F * 2; // 64 MB
    float* sblk = (float*)(ws + off);              off += 1024 * 4;

    k_prep<<<dim3(2048 + F + D), dim3(256), 0, stream>>>(
        (const float4*)x, (long)M * D / 4, partials,
        w1, w1q, sw1, rs1, w2, w2q, sw2, rs2);
    k_quant_act<<<dim3(2048), dim3(256), 0, stream>>>(
        (const float4*)x, (char4*)xi, (long)M * D / 4, partials, slots);
    // GEMM1 single pass: relu -> block-scaled u16 + block/global max
    k_gemm_i8<3, 256, 8><<<dim3(F / 128, M / 256), dim3(512), 0, stream>>>(
        xi, w1q, sw1, rs1, b1, slots + 0, nullptr, h16, sblk, slots + 1,
        M, F, (long)D);
    // u16 -> final uint8 units (offset -128)
    k_requant<<<dim3(2048), dim3(256), 0, stream>>>(
        (const ushort4*)h16, (char4*)hq, sblk, slots, (long)M * F / 4);
    // GEMM2: fp32 output
    k_gemm_i8<0, 128, 4><<<dim3(D / 128, M / 128), dim3(256), 0, stream>>>(
        hq, w2q, sw2, rs2, b2, slots + 1, out, nullptr, nullptr, nullptr,
        M, D, (long)F);

    (void)in_sizes; (void)n_in; (void)out_size; (void)ws_size;
}